// Round 9
// baseline (306.184 us; speedup 1.0000x reference)
//
#include <hip/hip_runtime.h>
#include <hip/hip_bf16.h>

#define TDIM 2048
#define BDIM 4
#define CDIM 1024
#define HDIM 16
#define DH   64

typedef __hip_bfloat16 bf16;
typedef __attribute__((ext_vector_type(8))) short bf16x8;
typedef __attribute__((ext_vector_type(4))) short bf16x4;
typedef __attribute__((ext_vector_type(4))) float f32x4;

// async global->LDS, 16B per lane; LDS dest = wave-uniform base + lane*16
__device__ __forceinline__ void async_ld16(const bf16* g, bf16* l) {
    __builtin_amdgcn_global_load_lds(
        (const __attribute__((address_space(1))) unsigned int*)g,
        (__attribute__((address_space(3))) unsigned int*)l, 16, 0, 0);
}

__device__ __forceinline__ unsigned short bf16bits(float x) {
    bf16 b = __float2bfloat16(x);
    return *(unsigned short*)&b;
}

// v_exp_f32 is natively 2^x; exp2f avoids __expf's extra 1/ln2 multiply
__device__ __forceinline__ float fast_exp2(float x) {
#if __has_builtin(__builtin_amdgcn_exp2f)
    return __builtin_amdgcn_exp2f(x);
#else
    return exp2f(x);
#endif
}

// 16x16x16 bf16 MFMA (k=16): verified working (passed correctness)
__device__ __forceinline__ f32x4 mfma_16x16x16_bf16(bf16x4 a, bf16x4 b, f32x4 c) {
#if __has_builtin(__builtin_amdgcn_mfma_f32_16x16x16_bf16)
    return __builtin_amdgcn_mfma_f32_16x16x16_bf16(a, b, c, 0, 0, 0);
#elif __has_builtin(__builtin_amdgcn_mfma_f32_16x16x16bf16_1k)
    return __builtin_amdgcn_mfma_f32_16x16x16bf16_1k(a, b, c, 0, 0, 0);
#else
    asm volatile("v_mfma_f32_16x16x16_bf16 %0, %1, %2, %0"
                 : "+v"(c) : "v"(a), "v"(b));
    return c;
#endif
}

// ---------------------------------------------------------------------------
__global__ void convert_x4(const float4* __restrict__ src, ushort4* __restrict__ dst, int n4) {
    int i = blockIdx.x * blockDim.x + threadIdx.x;
    if (i >= n4) return;
    float4 v = src[i];
    ushort4 o;
    o.x = bf16bits(v.x); o.y = bf16bits(v.y);
    o.z = bf16bits(v.z); o.w = bf16bits(v.w);
    dst[i] = o;
}

__global__ void convert_biases(const float* __restrict__ b0, const float* __restrict__ b1,
                               const float* __restrict__ b2, const float* __restrict__ b3,
                               bf16* __restrict__ dst) {
    int i = blockIdx.x * blockDim.x + threadIdx.x;   // 0..4095
    int which = i >> 10, j = i & 1023;
    const float* src = (which == 0) ? b0 : (which == 1) ? b1 : (which == 2) ? b2 : b3;
    dst[i] = __float2bfloat16(src[j]);
}

// ---------------------------------------------------------------------------
// LDS-tiled transpose, fused over Wq/Wk/Wv: z = which*16 + h.
// ---------------------------------------------------------------------------
__global__ __launch_bounds__(256) void transpose_qkv_kernel(
    const float* __restrict__ Wq, const float* __restrict__ Wk, const float* __restrict__ Wv,
    bf16* __restrict__ WqT, bf16* __restrict__ WkT, bf16* __restrict__ WvT) {
    __shared__ float tile[64][65];
    const int which = blockIdx.z >> 4, h = blockIdx.z & 15;
    const float* W  = ((which == 0) ? Wq  : (which == 1) ? Wk  : Wv)  + (size_t)h * CDIM * DH;
    bf16*        WT = ((which == 0) ? WqT : (which == 1) ? WkT : WvT) + (size_t)h * CDIM * DH;
    const int c0 = blockIdx.x * 64;
    for (int it = 0; it < 16; it++) {
        int e = it * 256 + threadIdx.x;
        int r = e >> 6, col = e & 63;
        tile[r][col] = W[(size_t)(c0 + r) * DH + col];
    }
    __syncthreads();
    for (int it = 0; it < 16; it++) {
        int e = it * 256 + threadIdx.x;
        int r = e >> 6, col = e & 63;
        WT[(size_t)r * CDIM + c0 + col] = __float2bfloat16(tile[col][r]);
    }
}

__global__ __launch_bounds__(256) void transpose_wo_kernel(
    const float* __restrict__ W, bf16* __restrict__ WT) {
    __shared__ float tile[64][65];
    const int c0 = blockIdx.x * 64, d0 = blockIdx.y * 64;
    for (int it = 0; it < 16; it++) {
        int e = it * 256 + threadIdx.x;
        int r = e >> 6, col = e & 63;
        tile[r][col] = W[(size_t)(c0 + r) * CDIM + d0 + col];
    }
    __syncthreads();
    for (int it = 0; it < 16; it++) {
        int e = it * 256 + threadIdx.x;
        int r = e >> 6, col = e & 63;
        WT[(size_t)(d0 + r) * CDIM + c0 + col] = __float2bfloat16(tile[col][r]);
    }
}

// V [bh][t][d] -> Vt [bh][d][t], 64x64 bf16 tiles
__global__ __launch_bounds__(256) void transpose_v_kernel(
    const bf16* __restrict__ V, bf16* __restrict__ Vt) {
    __shared__ unsigned short tile[64][65];
    const int bh = blockIdx.y, t0 = blockIdx.x * 64;
    const unsigned short* Vp  = (const unsigned short*)V + ((size_t)bh * TDIM + t0) * DH;
    unsigned short*       Vtp = (unsigned short*)Vt + (size_t)bh * DH * TDIM;
    for (int it = 0; it < 16; it++) {
        int e = it * 256 + threadIdx.x;
        int r = e >> 6, c = e & 63;
        tile[r][c] = Vp[(size_t)r * DH + c];
    }
    __syncthreads();
    for (int it = 0; it < 16; it++) {
        int e = it * 256 + threadIdx.x;
        int r = e >> 6, c = e & 63;
        Vtp[(size_t)r * TDIM + t0 + c] = tile[c][r];
    }
}

// ---------------------------------------------------------------------------
// 128x128 MFMA GEMM with global_load_lds staging (m97 pattern).
// QKV variant: z selects weight/bias/output.
// Q pre-scaled by (1/32)*log2(e) so attention can use native exp2.
// ---------------------------------------------------------------------------
__global__ __launch_bounds__(256) void proj_qkv_kernel(
    const bf16* __restrict__ X,
    const bf16* __restrict__ WqT, const bf16* __restrict__ WkT, const bf16* __restrict__ WvT,
    const bf16* __restrict__ bq,  const bf16* __restrict__ bk,  const bf16* __restrict__ bvv,
    bf16* __restrict__ Qo, bf16* __restrict__ Ko, bf16* __restrict__ Vo)
{
    const int z = blockIdx.z;
    const bf16* Bt   = (z == 0) ? WqT : (z == 1) ? WkT : WvT;
    const bf16* bias = (z == 0) ? bq  : (z == 1) ? bk  : bvv;

    __shared__ __align__(16) bf16 As[128 * 32];
    __shared__ __align__(16) bf16 Bs[128 * 32];

    const int tid  = threadIdx.x;
    const int lane = tid & 63;
    const int wave = tid >> 6;
    const int wr = wave >> 1, wc = wave & 1;
    const int l15 = lane & 15, quad = lane >> 4;

    const int blockM = blockIdx.y * 128;
    const int blockN = blockIdx.x * 128;

    f32x4 acc[4][4];
    for (int i = 0; i < 4; i++)
        for (int j = 0; j < 4; j++)
            acc[i][j] = (f32x4){0.f, 0.f, 0.f, 0.f};

    const int srow = lane >> 2, scol = (lane & 3) * 8;
    for (int k0 = 0; k0 < CDIM; k0 += 32) {
        for (int cc = 0; cc < 2; cc++) {
            int chunk = wave * 2 + cc;
            int row = chunk * 16 + srow;
            async_ld16(&X [(size_t)(blockM + row) * CDIM + k0 + scol], &As[chunk * 512]);
            async_ld16(&Bt[(size_t)(blockN + row) * CDIM + k0 + scol], &Bs[chunk * 512]);
        }
        __syncthreads();

        bf16x8 af[4], bfr[4];
        for (int mi = 0; mi < 4; mi++)
            af[mi] = *(const bf16x8*)&As[(wr * 64 + mi * 16 + l15) * 32 + quad * 8];
        for (int ni = 0; ni < 4; ni++)
            bfr[ni] = *(const bf16x8*)&Bs[(wc * 64 + ni * 16 + l15) * 32 + quad * 8];

        for (int mi = 0; mi < 4; mi++)
            for (int ni = 0; ni < 4; ni++)
                acc[mi][ni] = __builtin_amdgcn_mfma_f32_16x16x32_bf16(
                    af[mi], bfr[ni], acc[mi][ni], 0, 0, 0);
        __syncthreads();
    }

    for (int mi = 0; mi < 4; mi++) {
        int mbase = blockM + wr * 64 + mi * 16 + quad * 4;
        for (int ni = 0; ni < 4; ni++) {
            int n = blockN + wc * 64 + ni * 16 + l15;
            float bval = __bfloat162float(bias[n]);
            int h = n >> 6, d = n & 63;
            for (int r = 0; r < 4; r++) {
                int mm = mbase + r;
                int b = mm >> 11, t = mm & 2047;
                float val = acc[mi][ni][r] + bval;
                size_t idx = (((size_t)b * HDIM + h) * TDIM + t) * DH + d;
                if (z == 0)      Qo[idx] = __float2bfloat16(val * 0.045084439f); // (1/32)*log2(e)
                else if (z == 1) Ko[idx] = __float2bfloat16(val);
                else             Vo[idx] = __float2bfloat16(val);
            }
        }
    }
}

// ---------------------------------------------------------------------------
// Output projection: Y[M,K] @ WoT[N,K]^T + bo -> fp32 Out
// ---------------------------------------------------------------------------
__global__ __launch_bounds__(256) void proj_out_kernel(
    const bf16* __restrict__ X, const bf16* __restrict__ Bt,
    const bf16* __restrict__ bias, float* __restrict__ Out)
{
    __shared__ __align__(16) bf16 As[128 * 32];
    __shared__ __align__(16) bf16 Bs[128 * 32];

    const int tid  = threadIdx.x;
    const int lane = tid & 63;
    const int wave = tid >> 6;
    const int wr = wave >> 1, wc = wave & 1;
    const int l15 = lane & 15, quad = lane >> 4;

    const int blockM = blockIdx.y * 128;
    const int blockN = blockIdx.x * 128;

    f32x4 acc[4][4];
    for (int i = 0; i < 4; i++)
        for (int j = 0; j < 4; j++)
            acc[i][j] = (f32x4){0.f, 0.f, 0.f, 0.f};

    const int srow = lane >> 2, scol = (lane & 3) * 8;
    for (int k0 = 0; k0 < CDIM; k0 += 32) {
        for (int cc = 0; cc < 2; cc++) {
            int chunk = wave * 2 + cc;
            int row = chunk * 16 + srow;
            async_ld16(&X [(size_t)(blockM + row) * CDIM + k0 + scol], &As[chunk * 512]);
            async_ld16(&Bt[(size_t)(blockN + row) * CDIM + k0 + scol], &Bs[chunk * 512]);
        }
        __syncthreads();

        bf16x8 af[4], bfr[4];
        for (int mi = 0; mi < 4; mi++)
            af[mi] = *(const bf16x8*)&As[(wr * 64 + mi * 16 + l15) * 32 + quad * 8];
        for (int ni = 0; ni < 4; ni++)
            bfr[ni] = *(const bf16x8*)&Bs[(wc * 64 + ni * 16 + l15) * 32 + quad * 8];

        for (int mi = 0; mi < 4; mi++)
            for (int ni = 0; ni < 4; ni++)
                acc[mi][ni] = __builtin_amdgcn_mfma_f32_16x16x32_bf16(
                    af[mi], bfr[ni], acc[mi][ni], 0, 0, 0);
        __syncthreads();
    }

    for (int mi = 0; mi < 4; mi++) {
        int mbase = blockM + wr * 64 + mi * 16 + quad * 4;
        for (int ni = 0; ni < 4; ni++) {
            int n = blockN + wc * 64 + ni * 16 + l15;
            float bval = __bfloat162float(bias[n]);
            for (int r = 0; r < 4; r++)
                Out[(size_t)(mbase + r) * CDIM + n] = acc[mi][ni][r] + bval;
        }
    }
}

// ---------------------------------------------------------------------------
// Flash attention, causal.  128-q tiles, 8 WAVES (512 thr, 16 q rows/wave),
// gload_lds/swizzle staging, 2-buffer single-barrier loop.
//
// Round-8 (92us) was latency-bound: 4 waves/block x 1024 blocks = 16 waves/CU
// ceiling, measured 19% occ ~= 1.5 waves/SIMD -> the QK->exp->PV dependent
// chain had nothing to overlap with.  8-wave q-split doubles the ceiling to
// 32 waves/CU (100%) and halves per-wave serial work.  r1's 512-thread
// attempt failed ONLY because __launch_bounds__(512,8) forced a 64-VGPR cap
// onto a loop with 16 prefetch VGPRs -> catastrophic spills; this version
// has gload_lds staging (no prefetch regs) and lands ~50 VGPR at cap 128
// (r5/r8 measured 48/52 for the same loop body), so 8 waves/SIMD fit
// naturally.  Staging halves per thread (512 thr: 1 K + 1 V async_ld16).
// Causal per wave: kdiag = 2qT + (wave>>2); tiles beyond kdiag skipped
// (waves still hit the barrier); diag tile masked with qloc=(wave&3)*16+l15.
// Swizzle: stage dest linear stride-64 rows; global SOURCE col8 inverse-
// permuted per-lane ((tid&7)^((tid>>3)&7)); LDS reads XOR col8 with (row&7).
// exp2: Q pre-scaled by (1/32)*log2(e); v_exp_f32 is natively 2^x.
// ---------------------------------------------------------------------------
__global__ __launch_bounds__(512, 4) void attn_kernel(
    const bf16* __restrict__ Q, const bf16* __restrict__ Kb,
    const bf16* __restrict__ Vt, bf16* __restrict__ Y)
{
    const int bh    = blockIdx.y;
    const int qT    = (int)gridDim.x - 1 - blockIdx.x;   // 0..15, heavy first
    const int qBase = qT * 128;
    const int tid  = threadIdx.x;
    const int lane = tid & 63, wave = tid >> 6;          // wave 0..7
    const int l15 = lane & 15, quad = lane >> 4;

    __shared__ __align__(16) bf16 smem[2 * 2 * 64 * 64];     // 32 KiB, 2 bufs
    // buf b: K at smem + b*8192, V at smem + b*8192 + 4096 (stride-64 rows)

    // Q B-fragments: this wave's 16 q rows = qBase + wave*16 + l15
    const size_t qrow = (size_t)bh * TDIM + qBase + wave * 16 + l15;
    const bf16x8 qf0 = *(const bf16x8*)&Q[qrow * DH + quad * 8];
    const bf16x8 qf1 = *(const bf16x8*)&Q[qrow * DH + 32 + quad * 8];

    // O^T accumulators: o[mt][r] -> d = mt*16+quad*4+r, q = l15
    f32x4 o[4];
    for (int mt = 0; mt < 4; mt++) o[mt] = (f32x4){0.f, 0.f, 0.f, 0.f};
    float lsum = 0.f;

    // --- staging geometry: 512 threads x 16B = one 64x64 tile per array ----
    // thread t: row = t>>3 (0..63), linear col8 = t&7; row&7 = (t>>3)&7.
    // inverse-swizzled source col8 = (t&7) ^ ((t>>3)&7)
    const int srow = tid >> 3;
    const int ssc  = (((tid & 7) ^ ((tid >> 3) & 7)) << 3);     // elem offset
    const bf16* kSrc0 = Kb + ((size_t)bh * TDIM + srow) * DH + ssc;   // +kt*64*DH
    const bf16* vSrc0 = Vt + ((size_t)bh * DH + srow) * TDIM + ssc;   // +kt*64

    // read-side swizzle constants
    const int swA   = l15 & 7;                         // row&7 for fragment rows
    const int kcol0 = ((quad ^ swA) << 3);             // logical col8=quad
    const int kcol1 = (((4 + quad) ^ swA) << 3);       // logical col8=4+quad
    const int u2    = quad >> 1, intra = ((quad & 1) << 2);

    const int nkt   = 2 * qT + 2;
    const int kdiag = 2 * qT + (wave >> 2);      // last causal tile for this wave
    const int qloc  = (wave & 3) * 16 + l15;     // q offset within diag 64-block

    // wave-uniform staging dest bases (each wave writes 8 rows = 1KB)
    bf16* kD0 = smem + (wave * 8) * 64;
    bf16* vD0 = smem + 4096 + (wave * 8) * 64;

#define STAGE(tile, buf)                                            \
    do {                                                            \
        async_ld16(kSrc0 + (size_t)(tile) * 64 * DH, kD0 + (buf) * 8192); \
        async_ld16(vSrc0 + (size_t)(tile) * 64,      vD0 + (buf) * 8192); \
    } while (0)

    STAGE(0, 0);
    __syncthreads();   // tile 0 resident

    int cur = 0;
    for (int kt = 0; kt < nkt; kt++) {
        if (kt + 1 < nkt) STAGE(kt + 1, cur ^ 1);   // issued early, drained by
                                                    // the trailing barrier
        if (kt <= kdiag) {
            const bf16* Ks = smem + cur * 8192;
            const bf16* Vs = Ks + 4096;
            const bool diag = (kt == kdiag);
            for (int nt = 0; nt < 4; nt++) {
                // K A-frags for this 16-key chunk (swizzled cols)
                bf16x8 kf0 = *(const bf16x8*)&Ks[(nt * 16 + l15) * 64 + kcol0];
                bf16x8 kf1 = *(const bf16x8*)&Ks[(nt * 16 + l15) * 64 + kcol1];
                // V A-frags (16x16x16): logical elem col nt*16+quad*4
                bf16x4 vA[4];
                for (int mt = 0; mt < 4; mt++)
                    vA[mt] = *(const bf16x4*)&Vs[(mt * 16 + l15) * 64 +
                                                 (((nt * 2 + u2) ^ swA) << 3) + intra];

                f32x4 s = (f32x4){0.f, 0.f, 0.f, 0.f};
                s = __builtin_amdgcn_mfma_f32_16x16x32_bf16(kf0, qf0, s, 0, 0, 0);
                s = __builtin_amdgcn_mfma_f32_16x16x32_bf16(kf1, qf1, s, 0, 0, 0);

                bf16x4 pb;
                for (int r = 0; r < 4; r++) {
                    float pe = fast_exp2(s[r]);
                    if (diag && (nt * 16 + quad * 4 + r > qloc)) pe = 0.f;
                    lsum += pe;
                    pb[r] = (short)bf16bits(pe);
                }
                for (int mt = 0; mt < 4; mt++)
                    o[mt] = mfma_16x16x16_bf16(vA[mt], pb, o[mt]);
            }
        }
        __syncthreads();   // drains kt+1 loads + protects buffer swap
        cur ^= 1;
    }
#undef STAGE

    // ---- epilogue: normalize, per-wave LDS transpose, coalesced store ----
    float v = lsum;
    v += __shfl_xor(v, 16, 64);
    v += __shfl_xor(v, 32, 64);
    const float inv = 1.0f / v;

    // o -> LDS wave-private slice: rows wave*16..+15, stride 72 (18.4KB < 32KB)
    unsigned short* sm = (unsigned short*)smem;
    for (int mt = 0; mt < 4; mt++) {
        unsigned short pk[4];
        for (int r = 0; r < 4; r++) pk[r] = bf16bits(o[mt][r] * inv);
        *(ushort4*)&sm[(wave * 16 + l15) * 72 + mt * 16 + quad * 4] = *(ushort4*)pk;
    }
    // same-wave readback, coalesced global store
    const int b = bh >> 4, h = bh & 15;
    const int qq = lane >> 2, part = lane & 3;
    const int t = qBase + wave * 16 + qq;
    uint4 c0 = *(const uint4*)&sm[(wave * 16 + qq) * 72 + part * 16];
    uint4 c1 = *(const uint4*)&sm[(wave * 16 + qq) * 72 + part * 16 + 8];
    *(uint4*)&Y[((size_t)b * TDIM + t) * CDIM + h * DH + part * 16]     = c0;
    *(uint4*)&Y[((size_t)b * TDIM + t) * CDIM + h * DH + part * 16 + 8] = c1;
}

// ---------------------------------------------------------------------------
extern "C" void kernel_launch(void* const* d_in, const int* in_sizes, int n_in,
                              void* d_out, int out_size, void* d_ws, size_t ws_size,
                              hipStream_t stream) {
    (void)in_sizes; (void)n_in; (void)out_size; (void)ws_size;

    char* ws = (char*)d_ws;
    const size_t SZ_BHTD = (size_t)BDIM * HDIM * TDIM * DH * sizeof(bf16);  // 16 MiB
    const size_t SZ_W    = (size_t)HDIM * CDIM * DH * sizeof(bf16);         // 2 MiB
    bf16* Qb  = (bf16*)(ws);
    bf16* Kb  = (bf16*)(ws + SZ_BHTD);
    bf16* Vt  = (bf16*)(ws + 2 * SZ_BHTD);
    bf16* Y   = (bf16*)(ws + 3 * SZ_BHTD);
    bf16* WqT = (bf16*)(ws + 4 * SZ_BHTD);
    bf16* WkT = (bf16*)(ws + 4 * SZ_BHTD + SZ_W);
    bf16* WvT = (bf16*)(ws + 4 * SZ_BHTD + 2 * SZ_W);
    bf16* WoT = (bf16*)(ws + 4 * SZ_BHTD + 3 * SZ_W);
    bf16* xC  = (bf16*)(ws + 4 * SZ_BHTD + 4 * SZ_W);                       // 16 MiB
    bf16* bqC = (bf16*)(ws + 5 * SZ_BHTD + 4 * SZ_W);
    bf16* bkC = bqC + 1024;
    bf16* bvC = bqC + 2048;
    bf16* boC = bqC + 3072;
    bf16* Vb  = (bf16*)d_out;   // scratch: V [bh][t][d] lives in d_out until proj_out

    const int nX4 = (BDIM * TDIM * CDIM) / 4;
    convert_x4<<<nX4 / 256, 256, 0, stream>>>((const float4*)d_in[0], (ushort4*)xC, nX4);
    convert_biases<<<16, 256, 0, stream>>>((const float*)d_in[2], (const float*)d_in[4],
                                           (const float*)d_in[6], (const float*)d_in[8], bqC);

    transpose_qkv_kernel<<<dim3(CDIM / 64, 1, 48), 256, 0, stream>>>(
        (const float*)d_in[1], (const float*)d_in[3], (const float*)d_in[5], WqT, WkT, WvT);
    transpose_wo_kernel<<<dim3(CDIM / 64, CDIM / 64), 256, 0, stream>>>(
        (const float*)d_in[7], WoT);

    dim3 gq(CDIM / 128, (BDIM * TDIM) / 128, 3);
    proj_qkv_kernel<<<gq, 256, 0, stream>>>(xC, WqT, WkT, WvT, bqC, bkC, bvC, Qb, Kb, Vb);

    transpose_v_kernel<<<dim3(TDIM / 64, BDIM * HDIM), 256, 0, stream>>>(Vb, Vt);

    attn_kernel<<<dim3(TDIM / 128, BDIM * HDIM), 512, 0, stream>>>(Qb, Kb, Vt, Y);

    proj_out_kernel<<<dim3(CDIM / 128, (BDIM * TDIM) / 128), 256, 0, stream>>>(
        Y, WoT, boC, (float*)d_out);
}

// Round 12
// 292.139 us; speedup vs baseline: 1.0481x; 1.0481x over previous
//
#include <hip/hip_runtime.h>
#include <hip/hip_bf16.h>

#define TDIM 2048
#define BDIM 4
#define CDIM 1024
#define HDIM 16
#define DH   64

typedef __hip_bfloat16 bf16;
typedef __attribute__((ext_vector_type(8))) short bf16x8;
typedef __attribute__((ext_vector_type(4))) short bf16x4;
typedef __attribute__((ext_vector_type(4))) float f32x4;

// async global->LDS, 16B per lane; LDS dest = wave-uniform base + lane*16
__device__ __forceinline__ void async_ld16(const bf16* g, bf16* l) {
    __builtin_amdgcn_global_load_lds(
        (const __attribute__((address_space(1))) unsigned int*)g,
        (__attribute__((address_space(3))) unsigned int*)l, 16, 0, 0);
}

__device__ __forceinline__ unsigned short bf16bits(float x) {
    bf16 b = __float2bfloat16(x);
    return *(unsigned short*)&b;
}

// v_exp_f32 is natively 2^x; exp2f avoids __expf's extra 1/ln2 multiply
__device__ __forceinline__ float fast_exp2(float x) {
#if __has_builtin(__builtin_amdgcn_exp2f)
    return __builtin_amdgcn_exp2f(x);
#else
    return exp2f(x);
#endif
}

// 16x16x16 bf16 MFMA (k=16): verified working (passed correctness)
__device__ __forceinline__ f32x4 mfma_16x16x16_bf16(bf16x4 a, bf16x4 b, f32x4 c) {
#if __has_builtin(__builtin_amdgcn_mfma_f32_16x16x16_bf16)
    return __builtin_amdgcn_mfma_f32_16x16x16_bf16(a, b, c, 0, 0, 0);
#elif __has_builtin(__builtin_amdgcn_mfma_f32_16x16x16bf16_1k)
    return __builtin_amdgcn_mfma_f32_16x16x16bf16_1k(a, b, c, 0, 0, 0);
#else
    asm volatile("v_mfma_f32_16x16x16_bf16 %0, %1, %2, %0"
                 : "+v"(c) : "v"(a), "v"(b));
    return c;
#endif
}

// ---------------------------------------------------------------------------
__global__ void convert_x4(const float4* __restrict__ src, ushort4* __restrict__ dst, int n4) {
    int i = blockIdx.x * blockDim.x + threadIdx.x;
    if (i >= n4) return;
    float4 v = src[i];
    ushort4 o;
    o.x = bf16bits(v.x); o.y = bf16bits(v.y);
    o.z = bf16bits(v.z); o.w = bf16bits(v.w);
    dst[i] = o;
}

__global__ void convert_biases(const float* __restrict__ b0, const float* __restrict__ b1,
                               const float* __restrict__ b2, const float* __restrict__ b3,
                               bf16* __restrict__ dst) {
    int i = blockIdx.x * blockDim.x + threadIdx.x;   // 0..4095
    int which = i >> 10, j = i & 1023;
    const float* src = (which == 0) ? b0 : (which == 1) ? b1 : (which == 2) ? b2 : b3;
    dst[i] = __float2bfloat16(src[j]);
}

// ---------------------------------------------------------------------------
// LDS-tiled transpose, fused over Wq/Wk/Wv: z = which*16 + h.
// ---------------------------------------------------------------------------
__global__ __launch_bounds__(256) void transpose_qkv_kernel(
    const float* __restrict__ Wq, const float* __restrict__ Wk, const float* __restrict__ Wv,
    bf16* __restrict__ WqT, bf16* __restrict__ WkT, bf16* __restrict__ WvT) {
    __shared__ float tile[64][65];
    const int which = blockIdx.z >> 4, h = blockIdx.z & 15;
    const float* W  = ((which == 0) ? Wq  : (which == 1) ? Wk  : Wv)  + (size_t)h * CDIM * DH;
    bf16*        WT = ((which == 0) ? WqT : (which == 1) ? WkT : WvT) + (size_t)h * CDIM * DH;
    const int c0 = blockIdx.x * 64;
    for (int it = 0; it < 16; it++) {
        int e = it * 256 + threadIdx.x;
        int r = e >> 6, col = e & 63;
        tile[r][col] = W[(size_t)(c0 + r) * DH + col];
    }
    __syncthreads();
    for (int it = 0; it < 16; it++) {
        int e = it * 256 + threadIdx.x;
        int r = e >> 6, col = e & 63;
        WT[(size_t)r * CDIM + c0 + col] = __float2bfloat16(tile[col][r]);
    }
}

__global__ __launch_bounds__(256) void transpose_wo_kernel(
    const float* __restrict__ W, bf16* __restrict__ WT) {
    __shared__ float tile[64][65];
    const int c0 = blockIdx.x * 64, d0 = blockIdx.y * 64;
    for (int it = 0; it < 16; it++) {
        int e = it * 256 + threadIdx.x;
        int r = e >> 6, col = e & 63;
        tile[r][col] = W[(size_t)(c0 + r) * CDIM + d0 + col];
    }
    __syncthreads();
    for (int it = 0; it < 16; it++) {
        int e = it * 256 + threadIdx.x;
        int r = e >> 6, col = e & 63;
        WT[(size_t)(d0 + r) * CDIM + c0 + col] = __float2bfloat16(tile[col][r]);
    }
}

// V [bh][t][d] -> Vt [bh][d][t], 64x64 bf16 tiles
__global__ __launch_bounds__(256) void transpose_v_kernel(
    const bf16* __restrict__ V, bf16* __restrict__ Vt) {
    __shared__ unsigned short tile[64][65];
    const int bh = blockIdx.y, t0 = blockIdx.x * 64;
    const unsigned short* Vp  = (const unsigned short*)V + ((size_t)bh * TDIM + t0) * DH;
    unsigned short*       Vtp = (unsigned short*)Vt + (size_t)bh * DH * TDIM;
    for (int it = 0; it < 16; it++) {
        int e = it * 256 + threadIdx.x;
        int r = e >> 6, c = e & 63;
        tile[r][c] = Vp[(size_t)r * DH + c];
    }
    __syncthreads();
    for (int it = 0; it < 16; it++) {
        int e = it * 256 + threadIdx.x;
        int r = e >> 6, c = e & 63;
        Vtp[(size_t)r * TDIM + t0 + c] = tile[c][r];
    }
}

// ---------------------------------------------------------------------------
// 128x128 MFMA GEMM with global_load_lds staging (m97 pattern).
// QKV variant: z selects weight/bias/output.
// Q pre-scaled by (1/32)*log2(e) so attention can use native exp2.
// ---------------------------------------------------------------------------
__global__ __launch_bounds__(256) void proj_qkv_kernel(
    const bf16* __restrict__ X,
    const bf16* __restrict__ WqT, const bf16* __restrict__ WkT, const bf16* __restrict__ WvT,
    const bf16* __restrict__ bq,  const bf16* __restrict__ bk,  const bf16* __restrict__ bvv,
    bf16* __restrict__ Qo, bf16* __restrict__ Ko, bf16* __restrict__ Vo)
{
    const int z = blockIdx.z;
    const bf16* Bt   = (z == 0) ? WqT : (z == 1) ? WkT : WvT;
    const bf16* bias = (z == 0) ? bq  : (z == 1) ? bk  : bvv;

    __shared__ __align__(16) bf16 As[128 * 32];
    __shared__ __align__(16) bf16 Bs[128 * 32];

    const int tid  = threadIdx.x;
    const int lane = tid & 63;
    const int wave = tid >> 6;
    const int wr = wave >> 1, wc = wave & 1;
    const int l15 = lane & 15, quad = lane >> 4;

    const int blockM = blockIdx.y * 128;
    const int blockN = blockIdx.x * 128;

    f32x4 acc[4][4];
    for (int i = 0; i < 4; i++)
        for (int j = 0; j < 4; j++)
            acc[i][j] = (f32x4){0.f, 0.f, 0.f, 0.f};

    const int srow = lane >> 2, scol = (lane & 3) * 8;
    for (int k0 = 0; k0 < CDIM; k0 += 32) {
        for (int cc = 0; cc < 2; cc++) {
            int chunk = wave * 2 + cc;
            int row = chunk * 16 + srow;
            async_ld16(&X [(size_t)(blockM + row) * CDIM + k0 + scol], &As[chunk * 512]);
            async_ld16(&Bt[(size_t)(blockN + row) * CDIM + k0 + scol], &Bs[chunk * 512]);
        }
        __syncthreads();

        bf16x8 af[4], bfr[4];
        for (int mi = 0; mi < 4; mi++)
            af[mi] = *(const bf16x8*)&As[(wr * 64 + mi * 16 + l15) * 32 + quad * 8];
        for (int ni = 0; ni < 4; ni++)
            bfr[ni] = *(const bf16x8*)&Bs[(wc * 64 + ni * 16 + l15) * 32 + quad * 8];

        for (int mi = 0; mi < 4; mi++)
            for (int ni = 0; ni < 4; ni++)
                acc[mi][ni] = __builtin_amdgcn_mfma_f32_16x16x32_bf16(
                    af[mi], bfr[ni], acc[mi][ni], 0, 0, 0);
        __syncthreads();
    }

    for (int mi = 0; mi < 4; mi++) {
        int mbase = blockM + wr * 64 + mi * 16 + quad * 4;
        for (int ni = 0; ni < 4; ni++) {
            int n = blockN + wc * 64 + ni * 16 + l15;
            float bval = __bfloat162float(bias[n]);
            int h = n >> 6, d = n & 63;
            for (int r = 0; r < 4; r++) {
                int mm = mbase + r;
                int b = mm >> 11, t = mm & 2047;
                float val = acc[mi][ni][r] + bval;
                size_t idx = (((size_t)b * HDIM + h) * TDIM + t) * DH + d;
                if (z == 0)      Qo[idx] = __float2bfloat16(val * 0.045084439f); // (1/32)*log2(e)
                else if (z == 1) Ko[idx] = __float2bfloat16(val);
                else             Vo[idx] = __float2bfloat16(val);
            }
        }
    }
}

// ---------------------------------------------------------------------------
// Output projection: Y[M,K] @ WoT[N,K]^T + bo -> fp32 Out
// ---------------------------------------------------------------------------
__global__ __launch_bounds__(256) void proj_out_kernel(
    const bf16* __restrict__ X, const bf16* __restrict__ Bt,
    const bf16* __restrict__ bias, float* __restrict__ Out)
{
    __shared__ __align__(16) bf16 As[128 * 32];
    __shared__ __align__(16) bf16 Bs[128 * 32];

    const int tid  = threadIdx.x;
    const int lane = tid & 63;
    const int wave = tid >> 6;
    const int wr = wave >> 1, wc = wave & 1;
    const int l15 = lane & 15, quad = lane >> 4;

    const int blockM = blockIdx.y * 128;
    const int blockN = blockIdx.x * 128;

    f32x4 acc[4][4];
    for (int i = 0; i < 4; i++)
        for (int j = 0; j < 4; j++)
            acc[i][j] = (f32x4){0.f, 0.f, 0.f, 0.f};

    const int srow = lane >> 2, scol = (lane & 3) * 8;
    for (int k0 = 0; k0 < CDIM; k0 += 32) {
        for (int cc = 0; cc < 2; cc++) {
            int chunk = wave * 2 + cc;
            int row = chunk * 16 + srow;
            async_ld16(&X [(size_t)(blockM + row) * CDIM + k0 + scol], &As[chunk * 512]);
            async_ld16(&Bt[(size_t)(blockN + row) * CDIM + k0 + scol], &Bs[chunk * 512]);
        }
        __syncthreads();

        bf16x8 af[4], bfr[4];
        for (int mi = 0; mi < 4; mi++)
            af[mi] = *(const bf16x8*)&As[(wr * 64 + mi * 16 + l15) * 32 + quad * 8];
        for (int ni = 0; ni < 4; ni++)
            bfr[ni] = *(const bf16x8*)&Bs[(wc * 64 + ni * 16 + l15) * 32 + quad * 8];

        for (int mi = 0; mi < 4; mi++)
            for (int ni = 0; ni < 4; ni++)
                acc[mi][ni] = __builtin_amdgcn_mfma_f32_16x16x32_bf16(
                    af[mi], bfr[ni], acc[mi][ni], 0, 0, 0);
        __syncthreads();
    }

    for (int mi = 0; mi < 4; mi++) {
        int mbase = blockM + wr * 64 + mi * 16 + quad * 4;
        for (int ni = 0; ni < 4; ni++) {
            int n = blockN + wc * 64 + ni * 16 + l15;
            float bval = __bfloat162float(bias[n]);
            for (int r = 0; r < 4; r++)
                Out[(size_t)(mbase + r) * CDIM + n] = acc[mi][ni][r] + bval;
        }
    }
}

// ---------------------------------------------------------------------------
// Flash attention, causal.  ROUND-8 STRUCTURE (best measured: 92us attn /
// 296.6 total) + T1 XCD-AWARE GRID SWIZZLE (the one new variable; setprio
// dropped after two container failures on that source -- diagnostic).
//
// Swizzle rationale: default round-robin puts consecutive blocks (same bh,
// sharing 512KB of K/V) on DIFFERENT XCDs -> each XCD's 4MB L2 sees all
// 64 bh (32MB working set), near-zero cross-block reuse; staging latency is
// L3/HBM-class (~400-900cy) and this kernel is latency-bound (MfmaUtil 22.6,
// occupancy 19.5).  Remap so all 16 q-tiles of a bh land on one XCD
// (lin%8 = XCD by HW round-robin): per-XCD K/V working set drops 8x to
// ~4MB -> staging mostly L2-local (~200cy).  Bijective, nwg%8==0,
// heavy-first (qT descending) preserved within each XCD.
// Rest identical to r8: 128-q tiles, 4 waves, 2 q-groups/wave (K/V fragment
// reads amortized across groups -- r9 proved the 8-wave split regresses),
// gload_lds swizzle staging, 2-buffer single-barrier loop.
// ---------------------------------------------------------------------------
__global__ __launch_bounds__(256, 4) void attn_kernel(
    const bf16* __restrict__ Q, const bf16* __restrict__ Kb,
    const bf16* __restrict__ Vt, bf16* __restrict__ Y)
{
    // XCD-aware decode: lin -> (bh, qT) such that lin%8 is constant per bh
    const int lin  = blockIdx.x + (int)gridDim.x * blockIdx.y;   // 0..1023
    const int slot = lin >> 3;                                   // 0..127
    const int bh   = (lin & 7) * 8 + (slot >> 4);                // 0..63
    const int qT   = 15 - (slot & 15);                           // heavy first
    const int qBase = qT * 128;
    const int tid  = threadIdx.x;
    const int lane = tid & 63, wave = tid >> 6;          // wave 0..3
    const int l15 = lane & 15, quad = lane >> 4;

    __shared__ __align__(16) bf16 smem[2 * 2 * 64 * 64];     // 32 KiB, 2 bufs
    // buf b: K at smem + b*8192, V at smem + b*8192 + 4096 (stride-64 rows)

    // Q B-fragments: group g rows = qBase + g*64 + wave*16 + l15
    bf16x8 qf[2][2];
    for (int g = 0; g < 2; g++) {
        const size_t qrow = (size_t)bh * TDIM + qBase + g * 64 + wave * 16 + l15;
        qf[g][0] = *(const bf16x8*)&Q[qrow * DH + quad * 8];
        qf[g][1] = *(const bf16x8*)&Q[qrow * DH + 32 + quad * 8];
    }

    // O^T accumulators: o[g][mt][r] -> d = mt*16+quad*4+r, q = l15
    f32x4 o[2][4];
    for (int g = 0; g < 2; g++)
        for (int mt = 0; mt < 4; mt++)
            o[g][mt] = (f32x4){0.f, 0.f, 0.f, 0.f};
    float lsum[2] = {0.f, 0.f};

    // --- staging geometry: wave w covers rows w*16 .. w*16+15 --------------
    // lane l: row = base + (l>>3); base%8==0 so row&7 == l>>3.
    // inverse-swizzled source col8 = (l&7) ^ (l>>3)  (per-lane constant)
    const int srow = (wave << 4) + (lane >> 3);
    const int ssc  = (((lane & 7) ^ (lane >> 3)) << 3);         // elem offset
    const bf16* kSrc0 = Kb + ((size_t)bh * TDIM + srow) * DH + ssc;   // +kt*64*DH, +8*DH
    const bf16* vSrc0 = Vt + ((size_t)bh * DH + srow) * TDIM + ssc;   // +kt*64,    +8*TDIM

    // read-side swizzle constants
    const int swA   = l15 & 7;                         // row&7 for fragment rows
    const int kcol0 = ((quad ^ swA) << 3);             // logical col8=quad
    const int kcol1 = (((4 + quad) ^ swA) << 3);       // logical col8=4+quad
    const int u2    = quad >> 1, intra = ((quad & 1) << 2);

    const int nkt  = 2 * qT + 2;
    const int qloc = wave * 16 + l15;    // q offset within a group's 64 rows

    // wave-private staging bases (buffer-relative)
    bf16* kD0 = smem + (wave * 16) * 64;
    bf16* vD0 = smem + 4096 + (wave * 16) * 64;

#define STAGE(tile, buf)                                            \
    do {                                                            \
        const bf16* kS_ = kSrc0 + (size_t)(tile) * 64 * DH;         \
        const bf16* vS_ = vSrc0 + (size_t)(tile) * 64;              \
        bf16* kD_ = kD0 + (buf) * 8192;                             \
        bf16* vD_ = vD0 + (buf) * 8192;                             \
        async_ld16(kS_,            kD_);                            \
        async_ld16(kS_ + 8 * DH,   kD_ + 8 * 64);                   \
        async_ld16(vS_,            vD_);                            \
        async_ld16(vS_ + 8 * TDIM, vD_ + 8 * 64);                   \
    } while (0)

    STAGE(0, 0);
    __syncthreads();   // tile 0 resident

    int cur = 0;
    for (int kt = 0; kt < nkt; kt++) {
        if (kt + 1 < nkt) STAGE(kt + 1, cur ^ 1);   // issued early, drained by
                                                    // the trailing barrier
        const bf16* Ks = smem + cur * 8192;
        const bf16* Vs = Ks + 4096;

        const int dg = kt - 2 * qT;   // <0: both full; 0: g0 diag; 1: g1 diag, g0 done
        for (int nt = 0; nt < 4; nt++) {
            // K A-frags for this 16-key chunk (swizzled cols, shared by groups)
            bf16x8 kf0 = *(const bf16x8*)&Ks[(nt * 16 + l15) * 64 + kcol0];
            bf16x8 kf1 = *(const bf16x8*)&Ks[(nt * 16 + l15) * 64 + kcol1];
            // V A-frags (16x16x16): logical elem col nt*16+quad*4
            bf16x4 vA[4];
            for (int mt = 0; mt < 4; mt++)
                vA[mt] = *(const bf16x4*)&Vs[(mt * 16 + l15) * 64 +
                                             (((nt * 2 + u2) ^ swA) << 3) + intra];

            for (int g = 0; g < 2; g++) {
                if (dg == 1 && g == 0) continue;      // group 0 causal range done
                f32x4 s = (f32x4){0.f, 0.f, 0.f, 0.f};
                s = __builtin_amdgcn_mfma_f32_16x16x32_bf16(kf0, qf[g][0], s, 0, 0, 0);
                s = __builtin_amdgcn_mfma_f32_16x16x32_bf16(kf1, qf[g][1], s, 0, 0, 0);

                const bool diag = (dg == g);
                bf16x4 pb;
                for (int r = 0; r < 4; r++) {
                    float pe = fast_exp2(s[r]);
                    if (diag && (nt * 16 + quad * 4 + r > qloc)) pe = 0.f;
                    lsum[g] += pe;
                    pb[r] = (short)bf16bits(pe);
                }
                for (int mt = 0; mt < 4; mt++)
                    o[g][mt] = mfma_16x16x16_bf16(vA[mt], pb, o[g][mt]);
            }
        }
        __syncthreads();   // drains kt+1 loads + protects buffer swap
        cur ^= 1;
    }
#undef STAGE

    // ---- epilogue: per group, normalize, LDS transpose, coalesced store ----
    const int b = bh >> 4, h = bh & 15;
    unsigned short* sm = (unsigned short*)smem;
    for (int g = 0; g < 2; g++) {
        float v = lsum[g];
        v += __shfl_xor(v, 16, 64);
        v += __shfl_xor(v, 32, 64);
        const float inv = 1.0f / v;

        // o -> LDS wave-private slice [q row][d col], stride 72
        for (int mt = 0; mt < 4; mt++) {
            unsigned short pk[4];
            for (int r = 0; r < 4; r++) pk[r] = bf16bits(o[g][mt][r] * inv);
            *(ushort4*)&sm[(wave * 16 + l15) * 72 + mt * 16 + quad * 4] = *(ushort4*)pk;
        }
        // same-wave readback, coalesced global store
        const int qq = lane >> 2, part = lane & 3;
        const int t = qBase + g * 64 + wave * 16 + qq;
        uint4 c0 = *(const uint4*)&sm[(wave * 16 + qq) * 72 + part * 16];
        uint4 c1 = *(const uint4*)&sm[(wave * 16 + qq) * 72 + part * 16 + 8];
        *(uint4*)&Y[((size_t)b * TDIM + t) * CDIM + h * DH + part * 16]     = c0;
        *(uint4*)&Y[((size_t)b * TDIM + t) * CDIM + h * DH + part * 16 + 8] = c1;
    }
}

// ---------------------------------------------------------------------------
extern "C" void kernel_launch(void* const* d_in, const int* in_sizes, int n_in,
                              void* d_out, int out_size, void* d_ws, size_t ws_size,
                              hipStream_t stream) {
    (void)in_sizes; (void)n_in; (void)out_size; (void)ws_size;

    char* ws = (char*)d_ws;
    const size_t SZ_BHTD = (size_t)BDIM * HDIM * TDIM * DH * sizeof(bf16);  // 16 MiB
    const size_t SZ_W    = (size_t)HDIM * CDIM * DH * sizeof(bf16);         // 2 MiB
    bf16* Qb  = (bf16*)(ws);
    bf16* Kb  = (bf16*)(ws + SZ_BHTD);
    bf16* Vt  = (bf16*)(ws + 2 * SZ_BHTD);
    bf16* Y   = (bf16*)(ws + 3 * SZ_BHTD);
    bf16* WqT = (bf16*)(ws + 4 * SZ_BHTD);
    bf16* WkT = (bf16*)(ws + 4 * SZ_BHTD + SZ_W);
    bf16* WvT = (bf16*)(ws + 4 * SZ_BHTD + 2 * SZ_W);
    bf16* WoT = (bf16*)(ws + 4 * SZ_BHTD + 3 * SZ_W);
    bf16* xC  = (bf16*)(ws + 4 * SZ_BHTD + 4 * SZ_W);                       // 16 MiB
    bf16* bqC = (bf16*)(ws + 5 * SZ_BHTD + 4 * SZ_W);
    bf16* bkC = bqC + 1024;
    bf16* bvC = bqC + 2048;
    bf16* boC = bqC + 3072;
    bf16* Vb  = (bf16*)d_out;   // scratch: V [bh][t][d] lives in d_out until proj_out

    const int nX4 = (BDIM * TDIM * CDIM) / 4;
    convert_x4<<<nX4 / 256, 256, 0, stream>>>((const float4*)d_in[0], (ushort4*)xC, nX4);
    convert_biases<<<16, 256, 0, stream>>>((const float*)d_in[2], (const float*)d_in[4],
                                           (const float*)d_in[6], (const float*)d_in[8], bqC);

    transpose_qkv_kernel<<<dim3(CDIM / 64, 1, 48), 256, 0, stream>>>(
        (const float*)d_in[1], (const float*)d_in[3], (const float*)d_in[5], WqT, WkT, WvT);
    transpose_wo_kernel<<<dim3(CDIM / 64, CDIM / 64), 256, 0, stream>>>(
        (const float*)d_in[7], WoT);

    dim3 gq(CDIM / 128, (BDIM * TDIM) / 128, 3);
    proj_qkv_kernel<<<gq, 256, 0, stream>>>(xC, WqT, WkT, WvT, bqC, bkC, bvC, Qb, Kb, Vb);

    transpose_v_kernel<<<dim3(TDIM / 64, BDIM * HDIM), 256, 0, stream>>>(Vb, Vt);

    attn_kernel<<<dim3(TDIM / 128, BDIM * HDIM), 256, 0, stream>>>(Qb, Kb, Vt, Y);

    proj_out_kernel<<<dim3(CDIM / 128, (BDIM * TDIM) / 128), 256, 0, stream>>>(
        Y, WoT, boC, (float*)d_out);
}

// Round 13
// 280.366 us; speedup vs baseline: 1.0921x; 1.0420x over previous
//
#include <hip/hip_runtime.h>
#include <hip/hip_bf16.h>

#define TDIM 2048
#define BDIM 4
#define CDIM 1024
#define HDIM 16
#define DH   64

typedef __hip_bfloat16 bf16;
typedef __attribute__((ext_vector_type(8))) short bf16x8;
typedef __attribute__((ext_vector_type(4))) short bf16x4;
typedef __attribute__((ext_vector_type(4))) float f32x4;

// async global->LDS, 16B per lane; LDS dest = wave-uniform base + lane*16
__device__ __forceinline__ void async_ld16(const bf16* g, bf16* l) {
    __builtin_amdgcn_global_load_lds(
        (const __attribute__((address_space(1))) unsigned int*)g,
        (__attribute__((address_space(3))) unsigned int*)l, 16, 0, 0);
}

__device__ __forceinline__ unsigned short bf16bits(float x) {
    bf16 b = __float2bfloat16(x);
    return *(unsigned short*)&b;
}

// v_exp_f32 is natively 2^x; exp2f avoids __expf's extra 1/ln2 multiply
__device__ __forceinline__ float fast_exp2(float x) {
#if __has_builtin(__builtin_amdgcn_exp2f)
    return __builtin_amdgcn_exp2f(x);
#else
    return exp2f(x);
#endif
}

// 16x16x16 bf16 MFMA (k=16): verified working (passed correctness)
__device__ __forceinline__ f32x4 mfma_16x16x16_bf16(bf16x4 a, bf16x4 b, f32x4 c) {
#if __has_builtin(__builtin_amdgcn_mfma_f32_16x16x16_bf16)
    return __builtin_amdgcn_mfma_f32_16x16x16_bf16(a, b, c, 0, 0, 0);
#elif __has_builtin(__builtin_amdgcn_mfma_f32_16x16x16bf16_1k)
    return __builtin_amdgcn_mfma_f32_16x16x16bf16_1k(a, b, c, 0, 0, 0);
#else
    asm volatile("v_mfma_f32_16x16x16_bf16 %0, %1, %2, %0"
                 : "+v"(c) : "v"(a), "v"(b));
    return c;
#endif
}

// ---------------------------------------------------------------------------
__global__ void convert_x4(const float4* __restrict__ src, ushort4* __restrict__ dst, int n4) {
    int i = blockIdx.x * blockDim.x + threadIdx.x;
    if (i >= n4) return;
    float4 v = src[i];
    ushort4 o;
    o.x = bf16bits(v.x); o.y = bf16bits(v.y);
    o.z = bf16bits(v.z); o.w = bf16bits(v.w);
    dst[i] = o;
}

__global__ void convert_biases(const float* __restrict__ b0, const float* __restrict__ b1,
                               const float* __restrict__ b2, const float* __restrict__ b3,
                               bf16* __restrict__ dst) {
    int i = blockIdx.x * blockDim.x + threadIdx.x;   // 0..4095
    int which = i >> 10, j = i & 1023;
    const float* src = (which == 0) ? b0 : (which == 1) ? b1 : (which == 2) ? b2 : b3;
    dst[i] = __float2bfloat16(src[j]);
}

// ---------------------------------------------------------------------------
// LDS-tiled transpose, fused over Wq/Wk/Wv: z = which*16 + h.
// ---------------------------------------------------------------------------
__global__ __launch_bounds__(256) void transpose_qkv_kernel(
    const float* __restrict__ Wq, const float* __restrict__ Wk, const float* __restrict__ Wv,
    bf16* __restrict__ WqT, bf16* __restrict__ WkT, bf16* __restrict__ WvT) {
    __shared__ float tile[64][65];
    const int which = blockIdx.z >> 4, h = blockIdx.z & 15;
    const float* W  = ((which == 0) ? Wq  : (which == 1) ? Wk  : Wv)  + (size_t)h * CDIM * DH;
    bf16*        WT = ((which == 0) ? WqT : (which == 1) ? WkT : WvT) + (size_t)h * CDIM * DH;
    const int c0 = blockIdx.x * 64;
    for (int it = 0; it < 16; it++) {
        int e = it * 256 + threadIdx.x;
        int r = e >> 6, col = e & 63;
        tile[r][col] = W[(size_t)(c0 + r) * DH + col];
    }
    __syncthreads();
    for (int it = 0; it < 16; it++) {
        int e = it * 256 + threadIdx.x;
        int r = e >> 6, col = e & 63;
        WT[(size_t)r * CDIM + c0 + col] = __float2bfloat16(tile[col][r]);
    }
}

__global__ __launch_bounds__(256) void transpose_wo_kernel(
    const float* __restrict__ W, bf16* __restrict__ WT) {
    __shared__ float tile[64][65];
    const int c0 = blockIdx.x * 64, d0 = blockIdx.y * 64;
    for (int it = 0; it < 16; it++) {
        int e = it * 256 + threadIdx.x;
        int r = e >> 6, col = e & 63;
        tile[r][col] = W[(size_t)(c0 + r) * CDIM + d0 + col];
    }
    __syncthreads();
    for (int it = 0; it < 16; it++) {
        int e = it * 256 + threadIdx.x;
        int r = e >> 6, col = e & 63;
        WT[(size_t)(d0 + r) * CDIM + c0 + col] = __float2bfloat16(tile[col][r]);
    }
}

// V [bh][t][d] -> Vt [bh][d][t], 64x64 bf16 tiles
__global__ __launch_bounds__(256) void transpose_v_kernel(
    const bf16* __restrict__ V, bf16* __restrict__ Vt) {
    __shared__ unsigned short tile[64][65];
    const int bh = blockIdx.y, t0 = blockIdx.x * 64;
    const unsigned short* Vp  = (const unsigned short*)V + ((size_t)bh * TDIM + t0) * DH;
    unsigned short*       Vtp = (unsigned short*)Vt + (size_t)bh * DH * TDIM;
    for (int it = 0; it < 16; it++) {
        int e = it * 256 + threadIdx.x;
        int r = e >> 6, c = e & 63;
        tile[r][c] = Vp[(size_t)r * DH + c];
    }
    __syncthreads();
    for (int it = 0; it < 16; it++) {
        int e = it * 256 + threadIdx.x;
        int r = e >> 6, c = e & 63;
        Vtp[(size_t)r * TDIM + t0 + c] = tile[c][r];
    }
}

// ---------------------------------------------------------------------------
// 128x128 MFMA GEMM with global_load_lds staging (m97 pattern).
// QKV variant: z selects weight/bias/output.
// Q pre-scaled by (1/32)*log2(e) so attention can use native exp2.
// T1 XCD swizzle (r12's proven attn win, same mechanism): default mapping
// has gridDim.x=8 -> lin%8 = N-tile -> XCD = N-column, so every XCD streams
// ALL of X (48MB L2-miss/XCD; A-panel fetches are L3-class ~400cy, exposed
// at the K-loop barrier).  Remap XCD = M-octant: per-XCD A working set = 8
// panels x 256KB = 2MB, L2-resident across its 24 reuses (8 N x 3 z);
// weights stream 6MB/XCD.  Bijective: 8 octants x 8 mloc x 8 n x 3 z = 1536.
// ---------------------------------------------------------------------------
__global__ __launch_bounds__(256) void proj_qkv_kernel(
    const bf16* __restrict__ X,
    const bf16* __restrict__ WqT, const bf16* __restrict__ WkT, const bf16* __restrict__ WvT,
    const bf16* __restrict__ bq,  const bf16* __restrict__ bk,  const bf16* __restrict__ bvv,
    bf16* __restrict__ Qo, bf16* __restrict__ Ko, bf16* __restrict__ Vo)
{
    // XCD-aware decode (lin%8 = XCD by HW round-robin)
    const int lin  = blockIdx.x + (int)gridDim.x * (blockIdx.y + (int)gridDim.y * blockIdx.z);
    const int xcd  = lin & 7;
    const int s    = lin >> 3;          // 0..191
    const int mloc = s & 7;             // M-tile within octant
    const int rest = s >> 3;            // 0..23
    const int nblk = rest & 7;          // N-tile
    const int z    = rest >> 3;         // 0..2

    const bf16* Bt   = (z == 0) ? WqT : (z == 1) ? WkT : WvT;
    const bf16* bias = (z == 0) ? bq  : (z == 1) ? bk  : bvv;

    __shared__ __align__(16) bf16 As[128 * 32];
    __shared__ __align__(16) bf16 Bs[128 * 32];

    const int tid  = threadIdx.x;
    const int lane = tid & 63;
    const int wave = tid >> 6;
    const int wr = wave >> 1, wc = wave & 1;
    const int l15 = lane & 15, quad = lane >> 4;

    const int blockM = (xcd * 8 + mloc) * 128;
    const int blockN = nblk * 128;

    f32x4 acc[4][4];
    for (int i = 0; i < 4; i++)
        for (int j = 0; j < 4; j++)
            acc[i][j] = (f32x4){0.f, 0.f, 0.f, 0.f};

    const int srow = lane >> 2, scol = (lane & 3) * 8;
    for (int k0 = 0; k0 < CDIM; k0 += 32) {
        for (int cc = 0; cc < 2; cc++) {
            int chunk = wave * 2 + cc;
            int row = chunk * 16 + srow;
            async_ld16(&X [(size_t)(blockM + row) * CDIM + k0 + scol], &As[chunk * 512]);
            async_ld16(&Bt[(size_t)(blockN + row) * CDIM + k0 + scol], &Bs[chunk * 512]);
        }
        __syncthreads();

        bf16x8 af[4], bfr[4];
        for (int mi = 0; mi < 4; mi++)
            af[mi] = *(const bf16x8*)&As[(wr * 64 + mi * 16 + l15) * 32 + quad * 8];
        for (int ni = 0; ni < 4; ni++)
            bfr[ni] = *(const bf16x8*)&Bs[(wc * 64 + ni * 16 + l15) * 32 + quad * 8];

        for (int mi = 0; mi < 4; mi++)
            for (int ni = 0; ni < 4; ni++)
                acc[mi][ni] = __builtin_amdgcn_mfma_f32_16x16x32_bf16(
                    af[mi], bfr[ni], acc[mi][ni], 0, 0, 0);
        __syncthreads();
    }

    for (int mi = 0; mi < 4; mi++) {
        int mbase = blockM + wr * 64 + mi * 16 + quad * 4;
        for (int ni = 0; ni < 4; ni++) {
            int n = blockN + wc * 64 + ni * 16 + l15;
            float bval = __bfloat162float(bias[n]);
            int h = n >> 6, d = n & 63;
            for (int r = 0; r < 4; r++) {
                int mm = mbase + r;
                int b = mm >> 11, t = mm & 2047;
                float val = acc[mi][ni][r] + bval;
                size_t idx = (((size_t)b * HDIM + h) * TDIM + t) * DH + d;
                if (z == 0)      Qo[idx] = __float2bfloat16(val * 0.045084439f); // (1/32)*log2(e)
                else if (z == 1) Ko[idx] = __float2bfloat16(val);
                else             Vo[idx] = __float2bfloat16(val);
            }
        }
    }
}

// ---------------------------------------------------------------------------
// Output projection: Y[M,K] @ WoT[N,K]^T + bo -> fp32 Out
// Same T1 XCD swizzle: XCD = M-octant (bijective 8x8x8 = 512).
// ---------------------------------------------------------------------------
__global__ __launch_bounds__(256) void proj_out_kernel(
    const bf16* __restrict__ X, const bf16* __restrict__ Bt,
    const bf16* __restrict__ bias, float* __restrict__ Out)
{
    const int lin  = blockIdx.x + (int)gridDim.x * blockIdx.y;   // 0..511
    const int xcd  = lin & 7;
    const int s    = lin >> 3;      // 0..63
    const int mloc = s & 7;
    const int nblk = s >> 3;        // 0..7

    __shared__ __align__(16) bf16 As[128 * 32];
    __shared__ __align__(16) bf16 Bs[128 * 32];

    const int tid  = threadIdx.x;
    const int lane = tid & 63;
    const int wave = tid >> 6;
    const int wr = wave >> 1, wc = wave & 1;
    const int l15 = lane & 15, quad = lane >> 4;

    const int blockM = (xcd * 8 + mloc) * 128;
    const int blockN = nblk * 128;

    f32x4 acc[4][4];
    for (int i = 0; i < 4; i++)
        for (int j = 0; j < 4; j++)
            acc[i][j] = (f32x4){0.f, 0.f, 0.f, 0.f};

    const int srow = lane >> 2, scol = (lane & 3) * 8;
    for (int k0 = 0; k0 < CDIM; k0 += 32) {
        for (int cc = 0; cc < 2; cc++) {
            int chunk = wave * 2 + cc;
            int row = chunk * 16 + srow;
            async_ld16(&X [(size_t)(blockM + row) * CDIM + k0 + scol], &As[chunk * 512]);
            async_ld16(&Bt[(size_t)(blockN + row) * CDIM + k0 + scol], &Bs[chunk * 512]);
        }
        __syncthreads();

        bf16x8 af[4], bfr[4];
        for (int mi = 0; mi < 4; mi++)
            af[mi] = *(const bf16x8*)&As[(wr * 64 + mi * 16 + l15) * 32 + quad * 8];
        for (int ni = 0; ni < 4; ni++)
            bfr[ni] = *(const bf16x8*)&Bs[(wc * 64 + ni * 16 + l15) * 32 + quad * 8];

        for (int mi = 0; mi < 4; mi++)
            for (int ni = 0; ni < 4; ni++)
                acc[mi][ni] = __builtin_amdgcn_mfma_f32_16x16x32_bf16(
                    af[mi], bfr[ni], acc[mi][ni], 0, 0, 0);
        __syncthreads();
    }

    for (int mi = 0; mi < 4; mi++) {
        int mbase = blockM + wr * 64 + mi * 16 + quad * 4;
        for (int ni = 0; ni < 4; ni++) {
            int n = blockN + wc * 64 + ni * 16 + l15;
            float bval = __bfloat162float(bias[n]);
            for (int r = 0; r < 4; r++)
                Out[(size_t)(mbase + r) * CDIM + n] = acc[mi][ni][r] + bval;
        }
    }
}

// ---------------------------------------------------------------------------
// Flash attention, causal.  r12 version unchanged (81.2us measured):
// 128-q tiles, 4 waves, 2 q-groups/wave, gload_lds swizzle staging,
// 2-buffer single-barrier loop, T1 XCD swizzle (FETCH 112->24.6MB).
// ---------------------------------------------------------------------------
__global__ __launch_bounds__(256, 4) void attn_kernel(
    const bf16* __restrict__ Q, const bf16* __restrict__ Kb,
    const bf16* __restrict__ Vt, bf16* __restrict__ Y)
{
    // XCD-aware decode: lin -> (bh, qT) such that lin%8 is constant per bh
    const int lin  = blockIdx.x + (int)gridDim.x * blockIdx.y;   // 0..1023
    const int slot = lin >> 3;                                   // 0..127
    const int bh   = (lin & 7) * 8 + (slot >> 4);                // 0..63
    const int qT   = 15 - (slot & 15);                           // heavy first
    const int qBase = qT * 128;
    const int tid  = threadIdx.x;
    const int lane = tid & 63, wave = tid >> 6;          // wave 0..3
    const int l15 = lane & 15, quad = lane >> 4;

    __shared__ __align__(16) bf16 smem[2 * 2 * 64 * 64];     // 32 KiB, 2 bufs
    // buf b: K at smem + b*8192, V at smem + b*8192 + 4096 (stride-64 rows)

    // Q B-fragments: group g rows = qBase + g*64 + wave*16 + l15
    bf16x8 qf[2][2];
    for (int g = 0; g < 2; g++) {
        const size_t qrow = (size_t)bh * TDIM + qBase + g * 64 + wave * 16 + l15;
        qf[g][0] = *(const bf16x8*)&Q[qrow * DH + quad * 8];
        qf[g][1] = *(const bf16x8*)&Q[qrow * DH + 32 + quad * 8];
    }

    // O^T accumulators: o[g][mt][r] -> d = mt*16+quad*4+r, q = l15
    f32x4 o[2][4];
    for (int g = 0; g < 2; g++)
        for (int mt = 0; mt < 4; mt++)
            o[g][mt] = (f32x4){0.f, 0.f, 0.f, 0.f};
    float lsum[2] = {0.f, 0.f};

    // --- staging geometry: wave w covers rows w*16 .. w*16+15 --------------
    // lane l: row = base + (l>>3); base%8==0 so row&7 == l>>3.
    // inverse-swizzled source col8 = (l&7) ^ (l>>3)  (per-lane constant)
    const int srow = (wave << 4) + (lane >> 3);
    const int ssc  = (((lane & 7) ^ (lane >> 3)) << 3);         // elem offset
    const bf16* kSrc0 = Kb + ((size_t)bh * TDIM + srow) * DH + ssc;   // +kt*64*DH, +8*DH
    const bf16* vSrc0 = Vt + ((size_t)bh * DH + srow) * TDIM + ssc;   // +kt*64,    +8*TDIM

    // read-side swizzle constants
    const int swA   = l15 & 7;                         // row&7 for fragment rows
    const int kcol0 = ((quad ^ swA) << 3);             // logical col8=quad
    const int kcol1 = (((4 + quad) ^ swA) << 3);       // logical col8=4+quad
    const int u2    = quad >> 1, intra = ((quad & 1) << 2);

    const int nkt  = 2 * qT + 2;
    const int qloc = wave * 16 + l15;    // q offset within a group's 64 rows

    // wave-private staging bases (buffer-relative)
    bf16* kD0 = smem + (wave * 16) * 64;
    bf16* vD0 = smem + 4096 + (wave * 16) * 64;

#define STAGE(tile, buf)                                            \
    do {                                                            \
        const bf16* kS_ = kSrc0 + (size_t)(tile) * 64 * DH;         \
        const bf16* vS_ = vSrc0 + (size_t)(tile) * 64;              \
        bf16* kD_ = kD0 + (buf) * 8192;                             \
        bf16* vD_ = vD0 + (buf) * 8192;                             \
        async_ld16(kS_,            kD_);                            \
        async_ld16(kS_ + 8 * DH,   kD_ + 8 * 64);                   \
        async_ld16(vS_,            vD_);                            \
        async_ld16(vS_ + 8 * TDIM, vD_ + 8 * 64);                   \
    } while (0)

    STAGE(0, 0);
    __syncthreads();   // tile 0 resident

    int cur = 0;
    for (int kt = 0; kt < nkt; kt++) {
        if (kt + 1 < nkt) STAGE(kt + 1, cur ^ 1);   // issued early, drained by
                                                    // the trailing barrier
        const bf16* Ks = smem + cur * 8192;
        const bf16* Vs = Ks + 4096;

        const int dg = kt - 2 * qT;   // <0: both full; 0: g0 diag; 1: g1 diag, g0 done
        for (int nt = 0; nt < 4; nt++) {
            // K A-frags for this 16-key chunk (swizzled cols, shared by groups)
            bf16x8 kf0 = *(const bf16x8*)&Ks[(nt * 16 + l15) * 64 + kcol0];
            bf16x8 kf1 = *(const bf16x8*)&Ks[(nt * 16 + l15) * 64 + kcol1];
            // V A-frags (16x16x16): logical elem col nt*16+quad*4
            bf16x4 vA[4];
            for (int mt = 0; mt < 4; mt++)
                vA[mt] = *(const bf16x4*)&Vs[(mt * 16 + l15) * 64 +
                                             (((nt * 2 + u2) ^ swA) << 3) + intra];

            for (int g = 0; g < 2; g++) {
                if (dg == 1 && g == 0) continue;      // group 0 causal range done
                f32x4 s = (f32x4){0.f, 0.f, 0.f, 0.f};
                s = __builtin_amdgcn_mfma_f32_16x16x32_bf16(kf0, qf[g][0], s, 0, 0, 0);
                s = __builtin_amdgcn_mfma_f32_16x16x32_bf16(kf1, qf[g][1], s, 0, 0, 0);

                const bool diag = (dg == g);
                bf16x4 pb;
                for (int r = 0; r < 4; r++) {
                    float pe = fast_exp2(s[r]);
                    if (diag && (nt * 16 + quad * 4 + r > qloc)) pe = 0.f;
                    lsum[g] += pe;
                    pb[r] = (short)bf16bits(pe);
                }
                for (int mt = 0; mt < 4; mt++)
                    o[g][mt] = mfma_16x16x16_bf16(vA[mt], pb, o[g][mt]);
            }
        }
        __syncthreads();   // drains kt+1 loads + protects buffer swap
        cur ^= 1;
    }
#undef STAGE

    // ---- epilogue: per group, normalize, LDS transpose, coalesced store ----
    const int b = bh >> 4, h = bh & 15;
    unsigned short* sm = (unsigned short*)smem;
    for (int g = 0; g < 2; g++) {
        float v = lsum[g];
        v += __shfl_xor(v, 16, 64);
        v += __shfl_xor(v, 32, 64);
        const float inv = 1.0f / v;

        // o -> LDS wave-private slice [q row][d col], stride 72
        for (int mt = 0; mt < 4; mt++) {
            unsigned short pk[4];
            for (int r = 0; r < 4; r++) pk[r] = bf16bits(o[g][mt][r] * inv);
            *(ushort4*)&sm[(wave * 16 + l15) * 72 + mt * 16 + quad * 4] = *(ushort4*)pk;
        }
        // same-wave readback, coalesced global store
        const int qq = lane >> 2, part = lane & 3;
        const int t = qBase + g * 64 + wave * 16 + qq;
        uint4 c0 = *(const uint4*)&sm[(wave * 16 + qq) * 72 + part * 16];
        uint4 c1 = *(const uint4*)&sm[(wave * 16 + qq) * 72 + part * 16 + 8];
        *(uint4*)&Y[((size_t)b * TDIM + t) * CDIM + h * DH + part * 16]     = c0;
        *(uint4*)&Y[((size_t)b * TDIM + t) * CDIM + h * DH + part * 16 + 8] = c1;
    }
}

// ---------------------------------------------------------------------------
extern "C" void kernel_launch(void* const* d_in, const int* in_sizes, int n_in,
                              void* d_out, int out_size, void* d_ws, size_t ws_size,
                              hipStream_t stream) {
    (void)in_sizes; (void)n_in; (void)out_size; (void)ws_size;

    char* ws = (char*)d_ws;
    const size_t SZ_BHTD = (size_t)BDIM * HDIM * TDIM * DH * sizeof(bf16);  // 16 MiB
    const size_t SZ_W    = (size_t)HDIM * CDIM * DH * sizeof(bf16);         // 2 MiB
    bf16* Qb  = (bf16*)(ws);
    bf16* Kb  = (bf16*)(ws + SZ_BHTD);
    bf16* Vt  = (bf16*)(ws + 2 * SZ_BHTD);
    bf16* Y   = (bf16*)(ws + 3 * SZ_BHTD);
    bf16* WqT = (bf16*)(ws + 4 * SZ_BHTD);
    bf16* WkT = (bf16*)(ws + 4 * SZ_BHTD + SZ_W);
    bf16* WvT = (bf16*)(ws + 4 * SZ_BHTD + 2 * SZ_W);
    bf16* WoT = (bf16*)(ws + 4 * SZ_BHTD + 3 * SZ_W);
    bf16* xC  = (bf16*)(ws + 4 * SZ_BHTD + 4 * SZ_W);                       // 16 MiB
    bf16* bqC = (bf16*)(ws + 5 * SZ_BHTD + 4 * SZ_W);
    bf16* bkC = bqC + 1024;
    bf16* bvC = bqC + 2048;
    bf16* boC = bqC + 3072;
    bf16* Vb  = (bf16*)d_out;   // scratch: V [bh][t][d] lives in d_out until proj_out

    const int nX4 = (BDIM * TDIM * CDIM) / 4;
    convert_x4<<<nX4 / 256, 256, 0, stream>>>((const float4*)d_in[0], (ushort4*)xC, nX4);
    convert_biases<<<16, 256, 0, stream>>>((const float*)d_in[2], (const float*)d_in[4],
                                           (const float*)d_in[6], (const float*)d_in[8], bqC);

    transpose_qkv_kernel<<<dim3(CDIM / 64, 1, 48), 256, 0, stream>>>(
        (const float*)d_in[1], (const float*)d_in[3], (const float*)d_in[5], WqT, WkT, WvT);
    transpose_wo_kernel<<<dim3(CDIM / 64, CDIM / 64), 256, 0, stream>>>(
        (const float*)d_in[7], WoT);

    dim3 gq(CDIM / 128, (BDIM * TDIM) / 128, 3);
    proj_qkv_kernel<<<gq, 256, 0, stream>>>(xC, WqT, WkT, WvT, bqC, bkC, bvC, Qb, Kb, Vb);

    transpose_v_kernel<<<dim3(TDIM / 64, BDIM * HDIM), 256, 0, stream>>>(Vb, Vt);

    attn_kernel<<<dim3(TDIM / 128, BDIM * HDIM), 256, 0, stream>>>(Qb, Kb, Vt, Y);

    proj_out_kernel<<<dim3(CDIM / 128, (BDIM * TDIM) / 128), 256, 0, stream>>>(
        Y, WoT, boC, (float*)d_out);
}